// Round 5
// baseline (71.207 us; speedup 1.0000x reference)
//
#include <hip/hip_runtime.h>
#include <hip/hip_bf16.h>

// ODECell fused single kernel, v2: transposed x-tile in LDS (conflict-free reads).
// out[b][u] = Euler^6 of x' = -OMEGA*x + fA - x*fs, where
//   f[b,u,d] = sigmoid(sigma[u,d]*(inputs[b,d]-mu[u,d]))
//   fA = sum_d f*A[u,d], fs = sum_d f
// B=2048, U=128, D=128, all f32.
//
// Block = 64 batches x 8 units, 256 threads (4 waves, 2 u per thread).
// x tile stored TRANSPOSED xl[d][b] with row stride 65 words:
//   hot-loop read xl[d*65+lane] -> bank (d+lane)%32, 2 lanes/bank = free.
// P=-log2e*sigma, Q=log2e*sigma*mu in LDS (uniform-address broadcast reads).
// A rows via wave-uniform s_load. Grid 512.

#define BATCH 2048
#define UNITS 128
#define IDIM  128
#define L2E   1.4426950408889634f

#define BTILE 64
#define UTILE 8
#define XSTRIDE 65   // word stride between d-rows; 65%32=1 -> conflict-free columns

__global__ __launch_bounds__(256) void ode_fused(
    const float* __restrict__ inputs,  // [B][D]
    const float* __restrict__ state,   // [B][U]
    const float* __restrict__ A,       // [U][D]
    const float* __restrict__ sigma,   // [U][D]
    const float* __restrict__ mu,      // [U][D]
    float* __restrict__ out)           // [B][U]
{
    __shared__ float  xl[IDIM * XSTRIDE];  // 33280 B, xl[d*65 + b_local]
    __shared__ float2 pq[UTILE][IDIM];     // 8192 B

    const int tid  = threadIdx.x;
    const int lane = tid & 63;
    const int wave = __builtin_amdgcn_readfirstlane(tid >> 6);
    const int bx   = blockIdx.x;
    const int b0   = (bx & 31) * BTILE;    // stride-32 grid: b-tile stays XCD-local
    const int u0   = (bx >> 5) * UTILE;

    // ---- stage inputs tile (64 b x 128 d) transposed into LDS ----
    // coalesced float4 loads; transpose writes are 4-way (once, amortized)
    {
        const float4* in4 = (const float4*)(inputs + b0 * IDIM);
        const int c4 = tid & 31;           // which float4 within the row
        int r = tid >> 5;                  // which b row
        #pragma unroll
        for (int k = 0; k < 8; ++k, r += 8) {
            float4 v = in4[r * (IDIM / 4) + c4];
            const int d = c4 * 4;
            xl[(d + 0) * XSTRIDE + r] = v.x;
            xl[(d + 1) * XSTRIDE + r] = v.y;
            xl[(d + 2) * XSTRIDE + r] = v.z;
            xl[(d + 3) * XSTRIDE + r] = v.w;
        }
    }
    // ---- P,Q for the block's 8 u's ----
    {
        #pragma unroll
        for (int k = 0; k < 4; ++k) {
            const int idx = k * 256 + tid;        // [0,1024)
            const int uu = idx >> 7, dd = idx & 127;
            const float s = sigma[(u0 + uu) * IDIM + dd];
            const float m = mu[(u0 + uu) * IDIM + dd];
            pq[uu][dd] = make_float2(-L2E * s, L2E * s * m);
        }
    }
    __syncthreads();

    const int la = wave * 2, lb = la + 1;         // local u indices
    const int ua = u0 + la, ub = u0 + lb;
    const float* __restrict__ Aa = A + ua * IDIM; // wave-uniform -> s_load
    const float* __restrict__ Ab = A + ub * IDIM;

    float fAa0 = 0.f, fAa1 = 0.f, fsa0 = 0.f, fsa1 = 0.f;
    float fAb0 = 0.f, fAb1 = 0.f, fsb0 = 0.f, fsb1 = 0.f;

    const float* __restrict__ xcol = xl + lane;
    #pragma unroll 2
    for (int d = 0; d < IDIM; d += 4) {
        const float x0 = xcol[(d + 0) * XSTRIDE];   // bank (d+lane)%32: free
        const float x1 = xcol[(d + 1) * XSTRIDE];
        const float x2 = xcol[(d + 2) * XSTRIDE];
        const float x3 = xcol[(d + 3) * XSTRIDE];
        const float4 pa01 = *(const float4*)&pq[la][d];     // {p0,q0,p1,q1} broadcast
        const float4 pa23 = *(const float4*)&pq[la][d + 2];
        const float4 pb01 = *(const float4*)&pq[lb][d];
        const float4 pb23 = *(const float4*)&pq[lb][d + 2];
        const float4 a4a  = *(const float4*)(Aa + d);
        const float4 a4b  = *(const float4*)(Ab + d);

        const float fa0 = __builtin_amdgcn_rcpf(1.0f + __builtin_amdgcn_exp2f(fmaf(pa01.x, x0, pa01.y)));
        const float fa1 = __builtin_amdgcn_rcpf(1.0f + __builtin_amdgcn_exp2f(fmaf(pa01.z, x1, pa01.w)));
        const float fa2 = __builtin_amdgcn_rcpf(1.0f + __builtin_amdgcn_exp2f(fmaf(pa23.x, x2, pa23.y)));
        const float fa3 = __builtin_amdgcn_rcpf(1.0f + __builtin_amdgcn_exp2f(fmaf(pa23.z, x3, pa23.w)));
        const float fb0 = __builtin_amdgcn_rcpf(1.0f + __builtin_amdgcn_exp2f(fmaf(pb01.x, x0, pb01.y)));
        const float fb1 = __builtin_amdgcn_rcpf(1.0f + __builtin_amdgcn_exp2f(fmaf(pb01.z, x1, pb01.w)));
        const float fb2 = __builtin_amdgcn_rcpf(1.0f + __builtin_amdgcn_exp2f(fmaf(pb23.x, x2, pb23.y)));
        const float fb3 = __builtin_amdgcn_rcpf(1.0f + __builtin_amdgcn_exp2f(fmaf(pb23.z, x3, pb23.w)));

        fAa0 = fmaf(fa0, a4a.x, fAa0);  fAa1 = fmaf(fa1, a4a.y, fAa1);
        fAa0 = fmaf(fa2, a4a.z, fAa0);  fAa1 = fmaf(fa3, a4a.w, fAa1);
        fsa0 += fa0 + fa2;              fsa1 += fa1 + fa3;
        fAb0 = fmaf(fb0, a4b.x, fAb0);  fAb1 = fmaf(fb1, a4b.y, fAb1);
        fAb0 = fmaf(fb2, a4b.z, fAb0);  fAb1 = fmaf(fb3, a4b.w, fAb1);
        fsb0 += fb0 + fb2;              fsb1 += fb1 + fb3;
    }

    const float fA_a = fAa0 + fAa1, fs_a = fsa0 + fsa1;
    const float fA_b = fAb0 + fAb1, fs_b = fsb0 + fsb1;

    const int b = b0 + lane;
    float xa = state[b * UNITS + ua];
    float xb = state[b * UNITS + ub];
    const float dtu = (float)(0.1 / 6.0);
    const float ofa = 0.1f + fs_a;   // OMEGA + fs
    const float ofb = 0.1f + fs_b;
    #pragma unroll
    for (int k = 0; k < 6; ++k) {
        xa = fmaf(dtu, fmaf(-xa, ofa, fA_a), xa);
        xb = fmaf(dtu, fmaf(-xb, ofb, fA_b), xb);
    }
    out[b * UNITS + ua] = xa;
    out[b * UNITS + ub] = xb;
}

extern "C" void kernel_launch(void* const* d_in, const int* in_sizes, int n_in,
                              void* d_out, int out_size, void* d_ws, size_t ws_size,
                              hipStream_t stream) {
    const float* inputs = (const float*)d_in[0];
    const float* state  = (const float*)d_in[1];
    const float* A      = (const float*)d_in[2];
    const float* sigma  = (const float*)d_in[3];
    const float* mu     = (const float*)d_in[4];
    float* out = (float*)d_out;

    ode_fused<<<(BATCH / BTILE) * (UNITS / UTILE), 256, 0, stream>>>(
        inputs, state, A, sigma, mu, out);
}